// Round 1
// baseline (578.736 us; speedup 1.0000x reference)
//
#include <hip/hip_runtime.h>

#define NN 10000
#define EE 640000

typedef __attribute__((ext_vector_type(8))) short bf16x8;
typedef __attribute__((ext_vector_type(4))) float f32x4;

__device__ __forceinline__ short f2bf(float f) {
  union { float f; unsigned u; } v; v.f = f;
  unsigned u = v.u + 0x7fffu + ((v.u >> 16) & 1u);
  return (short)(u >> 16);
}

__device__ __forceinline__ float silu_f(float x) {
  return x / (1.0f + __expf(-x));
}

__device__ __forceinline__ f32x4 mfma16(bf16x8 a, bf16x8 b, f32x4 c) {
  return __builtin_amdgcn_mfma_f32_16x16x32_bf16(a, b, c, 0, 0, 0);
}

// ---------------------------------------------------------------------------
// Edge kernel: for 16-edge tiles, compute
//   m1 = silu([h[row]|h[col]] @ We1[:256] + radial*We1[256] + be1)
//   ef = silu(m1 @ We2 + be2)            -> atomicAdd into h_agg[row]
//   c1 = silu(ef @ Wc1 + bc1); s = c1@Wc2 -> atomicAdd diff*s, cnt into agg4[row]
// Block = 256 threads (4 waves); wave w owns output cols [32w, 32w+32).
// Weight B-fragments live in registers (preloaded once per block).
// ---------------------------------------------------------------------------
__global__ __launch_bounds__(256, 2)
void egcl_edge(const float* __restrict__ h, const float* __restrict__ y,
               const int* __restrict__ ei,
               const float* __restrict__ We1, const float* __restrict__ be1,
               const float* __restrict__ We2, const float* __restrict__ be2,
               const float* __restrict__ Wc1, const float* __restrict__ bc1,
               const float* __restrict__ Wc2,
               float* __restrict__ h_agg, float* __restrict__ agg4)
{
  const int tid  = threadIdx.x;
  const int wave = tid >> 6;
  const int lane = tid & 63;
  const int l16  = lane & 15;
  const int quad = lane >> 4;
  const int n0   = wave * 32;

  __shared__ short A_lds[16 * 264];   // 16 edges x K=256 (pad to 264)
  __shared__ short m1_lds[16 * 136];  // 16 x 128 (pad to 136)
  __shared__ short m2_lds[16 * 136];
  __shared__ float diff_lds[48];
  __shared__ float rad_lds[16];
  __shared__ int   row_lds[16];
  __shared__ float spart[4][16];

  // ---- per-wave weight fragments in registers ----
  // B frag layout (16x16x32): lane holds B[k = quad*8 + j][n = l16]
  bf16x8 wWe1[8][2];
  bf16x8 wWe2[4][2];
  bf16x8 wWc1[4][2];
  #pragma unroll
  for (int t = 0; t < 2; ++t) {
    const int n = n0 + t * 16 + l16;
    #pragma unroll
    for (int kc = 0; kc < 8; ++kc) {
      const float* p = We1 + (kc * 32 + quad * 8) * 128 + n;
      bf16x8 r;
      #pragma unroll
      for (int j = 0; j < 8; ++j) r[j] = f2bf(p[j * 128]);
      wWe1[kc][t] = r;
    }
    #pragma unroll
    for (int kc = 0; kc < 4; ++kc) {
      const float* p2 = We2 + (kc * 32 + quad * 8) * 128 + n;
      const float* p3 = Wc1 + (kc * 32 + quad * 8) * 128 + n;
      bf16x8 r2, r3;
      #pragma unroll
      for (int j = 0; j < 8; ++j) { r2[j] = f2bf(p2[j * 128]); r3[j] = f2bf(p3[j * 128]); }
      wWe2[kc][t] = r2;
      wWc1[kc][t] = r3;
    }
  }
  float w1last[2], b1v[2], b2v[2], bc1v[2], wc2v[2];
  #pragma unroll
  for (int t = 0; t < 2; ++t) {
    const int n = n0 + t * 16 + l16;
    w1last[t] = We1[256 * 128 + n];  // radial row of We1
    b1v[t]  = be1[n];
    b2v[t]  = be2[n];
    bc1v[t] = bc1[n];
    wc2v[t] = Wc2[n];
  }

  const int e_sub = tid >> 4;   // staging: edge-in-tile 0..15
  const int s16   = tid & 15;   // staging: 8-float chunk 0..15

  for (int tile = blockIdx.x; tile < EE / 16; tile += gridDim.x) {
    // ---------------- stage A (gather h[row], h[col] -> bf16 LDS) ----------
    {
      const int ge = tile * 16 + e_sub;
      const int r  = ei[ge];
      const int c  = ei[EE + ge];
      const float4* hr = (const float4*)(h + (size_t)r * 128);
      const float4* hc = (const float4*)(h + (size_t)c * 128);
      float4 a0 = hr[s16 * 2], a1 = hr[s16 * 2 + 1];
      float4 b0 = hc[s16 * 2], b1 = hc[s16 * 2 + 1];
      bf16x8 va, vb;
      va[0] = f2bf(a0.x); va[1] = f2bf(a0.y); va[2] = f2bf(a0.z); va[3] = f2bf(a0.w);
      va[4] = f2bf(a1.x); va[5] = f2bf(a1.y); va[6] = f2bf(a1.z); va[7] = f2bf(a1.w);
      vb[0] = f2bf(b0.x); vb[1] = f2bf(b0.y); vb[2] = f2bf(b0.z); vb[3] = f2bf(b0.w);
      vb[4] = f2bf(b1.x); vb[5] = f2bf(b1.y); vb[6] = f2bf(b1.z); vb[7] = f2bf(b1.w);
      *(bf16x8*)(&A_lds[e_sub * 264 + s16 * 8])       = va;
      *(bf16x8*)(&A_lds[e_sub * 264 + 128 + s16 * 8]) = vb;
      if (s16 == 0) {
        row_lds[e_sub] = r;
        const float dx = y[r * 3 + 0] - y[c * 3 + 0];
        const float dy = y[r * 3 + 1] - y[c * 3 + 1];
        const float dz = y[r * 3 + 2] - y[c * 3 + 2];
        diff_lds[e_sub * 3 + 0] = dx;
        diff_lds[e_sub * 3 + 1] = dy;
        diff_lds[e_sub * 3 + 2] = dz;
        rad_lds[e_sub] = dx * dx + dy * dy + dz * dz;
      }
    }
    __syncthreads();

    // ---------------- layer 1: K=256 ----------------
    {
      f32x4 acc00 = {0,0,0,0}, acc01 = {0,0,0,0}, acc10 = {0,0,0,0}, acc11 = {0,0,0,0};
      #pragma unroll
      for (int kc = 0; kc < 8; kc += 2) {
        bf16x8 aA = *(const bf16x8*)(&A_lds[l16 * 264 + kc * 32 + quad * 8]);
        bf16x8 aB = *(const bf16x8*)(&A_lds[l16 * 264 + (kc + 1) * 32 + quad * 8]);
        acc00 = mfma16(aA, wWe1[kc][0], acc00);
        acc10 = mfma16(aA, wWe1[kc][1], acc10);
        acc01 = mfma16(aB, wWe1[kc + 1][0], acc01);
        acc11 = mfma16(aB, wWe1[kc + 1][1], acc11);
      }
      #pragma unroll
      for (int r = 0; r < 4; ++r) {
        const int m = quad * 4 + r;                 // C/D: row = quad*4+reg, col = l16
        const float rad = rad_lds[m];
        float v0 = acc00[r] + acc01[r] + rad * w1last[0] + b1v[0];
        float v1 = acc10[r] + acc11[r] + rad * w1last[1] + b1v[1];
        m1_lds[m * 136 + n0 + l16]      = f2bf(silu_f(v0));
        m1_lds[m * 136 + n0 + 16 + l16] = f2bf(silu_f(v1));
      }
    }
    __syncthreads();

    // ---------------- layer 2: K=128 -> edge_feat ----------------
    float ef0[4], ef1[4];
    {
      f32x4 acc00 = {0,0,0,0}, acc01 = {0,0,0,0}, acc10 = {0,0,0,0}, acc11 = {0,0,0,0};
      #pragma unroll
      for (int kc = 0; kc < 4; kc += 2) {
        bf16x8 aA = *(const bf16x8*)(&m1_lds[l16 * 136 + kc * 32 + quad * 8]);
        bf16x8 aB = *(const bf16x8*)(&m1_lds[l16 * 136 + (kc + 1) * 32 + quad * 8]);
        acc00 = mfma16(aA, wWe2[kc][0], acc00);
        acc10 = mfma16(aA, wWe2[kc][1], acc10);
        acc01 = mfma16(aB, wWe2[kc + 1][0], acc01);
        acc11 = mfma16(aB, wWe2[kc + 1][1], acc11);
      }
      #pragma unroll
      for (int r = 0; r < 4; ++r) {
        const int m = quad * 4 + r;
        float v0 = silu_f(acc00[r] + acc01[r] + b2v[0]);
        float v1 = silu_f(acc10[r] + acc11[r] + b2v[1]);
        ef0[r] = v0; ef1[r] = v1;
        m2_lds[m * 136 + n0 + l16]      = f2bf(v0);
        m2_lds[m * 136 + n0 + 16 + l16] = f2bf(v1);
      }
    }
    __syncthreads();

    // h_agg scatter (fp32 atomics) — overlaps with layer 3 issue
    #pragma unroll
    for (int r = 0; r < 4; ++r) {
      const int m = quad * 4 + r;
      const int node = row_lds[m];
      atomicAdd(&h_agg[(size_t)node * 128 + n0 + l16],      ef0[r]);
      atomicAdd(&h_agg[(size_t)node * 128 + n0 + 16 + l16], ef1[r]);
    }

    // ---------------- layer 3: K=128 -> scalar s per edge ----------------
    {
      f32x4 acc00 = {0,0,0,0}, acc01 = {0,0,0,0}, acc10 = {0,0,0,0}, acc11 = {0,0,0,0};
      #pragma unroll
      for (int kc = 0; kc < 4; kc += 2) {
        bf16x8 aA = *(const bf16x8*)(&m2_lds[l16 * 136 + kc * 32 + quad * 8]);
        bf16x8 aB = *(const bf16x8*)(&m2_lds[l16 * 136 + (kc + 1) * 32 + quad * 8]);
        acc00 = mfma16(aA, wWc1[kc][0], acc00);
        acc10 = mfma16(aA, wWc1[kc][1], acc10);
        acc01 = mfma16(aB, wWc1[kc + 1][0], acc01);
        acc11 = mfma16(aB, wWc1[kc + 1][1], acc11);
      }
      float p[4];
      #pragma unroll
      for (int r = 0; r < 4; ++r) {
        float c0 = silu_f(acc00[r] + acc01[r] + bc1v[0]);
        float c1 = silu_f(acc10[r] + acc11[r] + bc1v[1]);
        p[r] = c0 * wc2v[0] + c1 * wc2v[1];
      }
      #pragma unroll
      for (int msk = 8; msk >= 1; msk >>= 1) {
        #pragma unroll
        for (int r = 0; r < 4; ++r) p[r] += __shfl_xor(p[r], msk, 64);
      }
      if (l16 == 0) {
        #pragma unroll
        for (int r = 0; r < 4; ++r) spart[wave][quad * 4 + r] = p[r];
      }
    }
    __syncthreads();

    if (tid < 16) {
      const float s = spart[0][tid] + spart[1][tid] + spart[2][tid] + spart[3][tid];
      const int node = row_lds[tid];
      atomicAdd(&agg4[node * 4 + 0], diff_lds[tid * 3 + 0] * s);
      atomicAdd(&agg4[node * 4 + 1], diff_lds[tid * 3 + 1] * s);
      atomicAdd(&agg4[node * 4 + 2], diff_lds[tid * 3 + 2] * s);
      atomicAdd(&agg4[node * 4 + 3], 1.0f);
    }
    __syncthreads();
  }
}

// ---------------------------------------------------------------------------
// Node kernel: h_out = h + silu([h|h_agg]@Wn1 + bn1) @ Wn2 + bn2
//              y_out = y + agg_sum / max(cnt,1)
// ---------------------------------------------------------------------------
__global__ __launch_bounds__(256, 2)
void egcl_node(const float* __restrict__ h, const float* __restrict__ y,
               const float* __restrict__ Wn1, const float* __restrict__ bn1,
               const float* __restrict__ Wn2, const float* __restrict__ bn2,
               const float* __restrict__ h_agg, const float* __restrict__ agg4,
               float* __restrict__ h_out, float* __restrict__ y_out)
{
  const int tid  = threadIdx.x;
  const int wave = tid >> 6;
  const int lane = tid & 63;
  const int l16  = lane & 15;
  const int quad = lane >> 4;
  const int n0   = wave * 32;

  __shared__ short A_lds[16 * 264];
  __shared__ short m1_lds[16 * 136];

  bf16x8 wWn1[8][2];
  bf16x8 wWn2[4][2];
  #pragma unroll
  for (int t = 0; t < 2; ++t) {
    const int n = n0 + t * 16 + l16;
    #pragma unroll
    for (int kc = 0; kc < 8; ++kc) {
      const float* p = Wn1 + (kc * 32 + quad * 8) * 128 + n;
      bf16x8 r;
      #pragma unroll
      for (int j = 0; j < 8; ++j) r[j] = f2bf(p[j * 128]);
      wWn1[kc][t] = r;
    }
    #pragma unroll
    for (int kc = 0; kc < 4; ++kc) {
      const float* p2 = Wn2 + (kc * 32 + quad * 8) * 128 + n;
      bf16x8 r2;
      #pragma unroll
      for (int j = 0; j < 8; ++j) r2[j] = f2bf(p2[j * 128]);
      wWn2[kc][t] = r2;
    }
  }
  float bn1v[2], bn2v[2];
  #pragma unroll
  for (int t = 0; t < 2; ++t) {
    const int n = n0 + t * 16 + l16;
    bn1v[t] = bn1[n];
    bn2v[t] = bn2[n];
  }

  const int node0 = blockIdx.x * 16;
  const int e_sub = tid >> 4;
  const int s16   = tid & 15;

  // stage A = [h | h_agg]
  {
    const int nd = node0 + e_sub;
    const float4* hr = (const float4*)(h + (size_t)nd * 128);
    const float4* ha = (const float4*)(h_agg + (size_t)nd * 128);
    float4 a0 = hr[s16 * 2], a1 = hr[s16 * 2 + 1];
    float4 b0 = ha[s16 * 2], b1 = ha[s16 * 2 + 1];
    bf16x8 va, vb;
    va[0] = f2bf(a0.x); va[1] = f2bf(a0.y); va[2] = f2bf(a0.z); va[3] = f2bf(a0.w);
    va[4] = f2bf(a1.x); va[5] = f2bf(a1.y); va[6] = f2bf(a1.z); va[7] = f2bf(a1.w);
    vb[0] = f2bf(b0.x); vb[1] = f2bf(b0.y); vb[2] = f2bf(b0.z); vb[3] = f2bf(b0.w);
    vb[4] = f2bf(b1.x); vb[5] = f2bf(b1.y); vb[6] = f2bf(b1.z); vb[7] = f2bf(b1.w);
    *(bf16x8*)(&A_lds[e_sub * 264 + s16 * 8])       = va;
    *(bf16x8*)(&A_lds[e_sub * 264 + 128 + s16 * 8]) = vb;
  }
  __syncthreads();

  // y_out (independent of MLP)
  if (tid < 16) {
    const int nd = node0 + tid;
    const float cnt = agg4[nd * 4 + 3];
    const float inv = 1.0f / fmaxf(cnt, 1.0f);
    y_out[nd * 3 + 0] = y[nd * 3 + 0] + agg4[nd * 4 + 0] * inv;
    y_out[nd * 3 + 1] = y[nd * 3 + 1] + agg4[nd * 4 + 1] * inv;
    y_out[nd * 3 + 2] = y[nd * 3 + 2] + agg4[nd * 4 + 2] * inv;
  }

  // layer 1: K=256
  {
    f32x4 acc00 = {0,0,0,0}, acc01 = {0,0,0,0}, acc10 = {0,0,0,0}, acc11 = {0,0,0,0};
    #pragma unroll
    for (int kc = 0; kc < 8; kc += 2) {
      bf16x8 aA = *(const bf16x8*)(&A_lds[l16 * 264 + kc * 32 + quad * 8]);
      bf16x8 aB = *(const bf16x8*)(&A_lds[l16 * 264 + (kc + 1) * 32 + quad * 8]);
      acc00 = mfma16(aA, wWn1[kc][0], acc00);
      acc10 = mfma16(aA, wWn1[kc][1], acc10);
      acc01 = mfma16(aB, wWn1[kc + 1][0], acc01);
      acc11 = mfma16(aB, wWn1[kc + 1][1], acc11);
    }
    #pragma unroll
    for (int r = 0; r < 4; ++r) {
      const int m = quad * 4 + r;
      float v0 = silu_f(acc00[r] + acc01[r] + bn1v[0]);
      float v1 = silu_f(acc10[r] + acc11[r] + bn1v[1]);
      m1_lds[m * 136 + n0 + l16]      = f2bf(v0);
      m1_lds[m * 136 + n0 + 16 + l16] = f2bf(v1);
    }
  }
  __syncthreads();

  // layer 2: K=128 + residual
  {
    f32x4 acc00 = {0,0,0,0}, acc01 = {0,0,0,0}, acc10 = {0,0,0,0}, acc11 = {0,0,0,0};
    #pragma unroll
    for (int kc = 0; kc < 4; kc += 2) {
      bf16x8 aA = *(const bf16x8*)(&m1_lds[l16 * 136 + kc * 32 + quad * 8]);
      bf16x8 aB = *(const bf16x8*)(&m1_lds[l16 * 136 + (kc + 1) * 32 + quad * 8]);
      acc00 = mfma16(aA, wWn2[kc][0], acc00);
      acc10 = mfma16(aA, wWn2[kc][1], acc10);
      acc01 = mfma16(aB, wWn2[kc + 1][0], acc01);
      acc11 = mfma16(aB, wWn2[kc + 1][1], acc11);
    }
    #pragma unroll
    for (int r = 0; r < 4; ++r) {
      const int m = quad * 4 + r;
      const int nd = node0 + m;
      const int na = n0 + l16;
      const int nb = n0 + 16 + l16;
      h_out[(size_t)nd * 128 + na] = h[(size_t)nd * 128 + na] + acc00[r] + acc01[r] + bn2v[0];
      h_out[(size_t)nd * 128 + nb] = h[(size_t)nd * 128 + nb] + acc10[r] + acc11[r] + bn2v[1];
    }
  }
}

extern "C" void kernel_launch(void* const* d_in, const int* in_sizes, int n_in,
                              void* d_out, int out_size, void* d_ws, size_t ws_size,
                              hipStream_t stream) {
  (void)in_sizes; (void)n_in; (void)out_size;
  const float* h   = (const float*)d_in[0];
  const float* y   = (const float*)d_in[1];
  const int*   ei  = (const int*)d_in[2];
  const float* We1 = (const float*)d_in[3];
  const float* be1 = (const float*)d_in[4];
  const float* We2 = (const float*)d_in[5];
  const float* be2 = (const float*)d_in[6];
  const float* Wc1 = (const float*)d_in[7];
  const float* bc1 = (const float*)d_in[8];
  const float* Wc2 = (const float*)d_in[9];
  const float* Wn1 = (const float*)d_in[10];
  const float* bn1 = (const float*)d_in[11];
  const float* Wn2 = (const float*)d_in[12];
  const float* bn2 = (const float*)d_in[13];

  float* h_out = (float*)d_out;
  float* y_out = h_out + (size_t)NN * 128;

  float* h_agg = (float*)d_ws;                    // NN x 128 fp32
  float* agg4  = h_agg + (size_t)NN * 128;        // NN x 4 fp32 (sum xyz, cnt)
  const size_t ws_need = (size_t)NN * 132 * sizeof(float);
  if (ws_size < ws_need) return;  // workspace too small — fail visibly, no OOB

  hipMemsetAsync(d_ws, 0, ws_need, stream);
  egcl_edge<<<2048, 256, 0, stream>>>(h, y, ei, We1, be1, We2, be2, Wc1, bc1, Wc2,
                                      h_agg, agg4);
  egcl_node<<<625, 256, 0, stream>>>(h, y, Wn1, bn1, Wn2, bn2, h_agg, agg4,
                                     h_out, y_out);
}